// Round 1
// baseline (234.417 us; speedup 1.0000x reference)
//
#include <hip/hip_runtime.h>

// MCANet: out = x * sigmoid(w1d[c, center] * mean_{h,w}(x[b,c,h,w]))
// The conv1x1+softmax branch in the reference is dead code (del y).
// x: (16, 512, 64, 64) f32; w1d: (512, 5) f32; center tap index = 2.

#define NC 512
#define HW 4096  // 64*64

__global__ __launch_bounds__(256) void mcanet_gate_kernel(
    const float* __restrict__ x,
    const float* __restrict__ w1d,
    float* __restrict__ out)
{
    const int plane = blockIdx.x;        // b*NC + c
    const int c = plane & (NC - 1);
    const long long base = (long long)plane * HW;
    const float4* __restrict__ xin = (const float4*)(x + base);
    float4* __restrict__ o = (float4*)(out + base);
    const int tid = threadIdx.x;

    // 4096 floats = 1024 float4s; 256 threads -> 4 float4 each (registers).
    float4 v0 = xin[tid];
    float4 v1 = xin[tid + 256];
    float4 v2 = xin[tid + 512];
    float4 v3 = xin[tid + 768];

    float s = (v0.x + v0.y + v0.z + v0.w)
            + (v1.x + v1.y + v1.z + v1.w)
            + (v2.x + v2.y + v2.z + v2.w)
            + (v3.x + v3.y + v3.z + v3.w);

    // Wave-level reduction (wave = 64 lanes on gfx950).
    #pragma unroll
    for (int off = 32; off > 0; off >>= 1)
        s += __shfl_down(s, off, 64);

    __shared__ float ws[4];
    __shared__ float gate_s;
    const int wave = tid >> 6;
    if ((tid & 63) == 0) ws[wave] = s;
    __syncthreads();
    if (tid == 0) {
        float tot = ws[0] + ws[1] + ws[2] + ws[3];
        float zc = w1d[c * 5 + 2] * (tot * (1.0f / (float)HW));
        gate_s = 1.0f / (1.0f + __expf(-zc));
    }
    __syncthreads();
    const float g = gate_s;

    v0.x *= g; v0.y *= g; v0.z *= g; v0.w *= g;
    v1.x *= g; v1.y *= g; v1.z *= g; v1.w *= g;
    v2.x *= g; v2.y *= g; v2.z *= g; v2.w *= g;
    v3.x *= g; v3.y *= g; v3.z *= g; v3.w *= g;

    o[tid]       = v0;
    o[tid + 256] = v1;
    o[tid + 512] = v2;
    o[tid + 768] = v3;
}

extern "C" void kernel_launch(void* const* d_in, const int* in_sizes, int n_in,
                              void* d_out, int out_size, void* d_ws, size_t ws_size,
                              hipStream_t stream) {
    const float* x    = (const float*)d_in[0];  // (16,512,64,64)
    // d_in[1] = w1x1 (unused), d_in[2] = b1x1 (unused)
    const float* w1d  = (const float*)d_in[3];  // (512,5)
    float* out = (float*)d_out;

    const int planes = 16 * NC;  // 8192 blocks
    mcanet_gate_kernel<<<planes, 256, 0, stream>>>(x, w1d, out);
}

// Round 3
// 224.190 us; speedup vs baseline: 1.0456x; 1.0456x over previous
//
#include <hip/hip_runtime.h>

// MCANet: out = x * sigmoid(w1d[c, center] * mean_{h,w}(x[b,c,h,w]))
// The conv1x1+softmax branch in the reference is dead code (del y).
// x: (16, 512, 64, 64) f32; w1d: (512, 5) f32; center tap index = 2.
//
// Streaming kernel: 134 MB read + 134 MB write, register-resident between
// the reduction and the scale (x is read exactly once). Non-temporal
// loads/stores: zero reuse, working set (268 MB) > LLC (256 MB) — skip
// cache allocation. NOTE: __builtin_nontemporal_* needs a Clang native
// vector type, not HIP's float4 struct.

#define NC 512
#define HW 4096  // 64*64

typedef float vf4 __attribute__((ext_vector_type(4)));

__global__ __launch_bounds__(256) void mcanet_gate_kernel(
    const float* __restrict__ x,
    const float* __restrict__ w1d,
    float* __restrict__ out)
{
    const int plane = blockIdx.x;        // b*NC + c
    const int c = plane & (NC - 1);
    const long long base = (long long)plane * HW;
    const vf4* __restrict__ xin = (const vf4*)(x + base);
    vf4* __restrict__ o = (vf4*)(out + base);
    const int tid = threadIdx.x;

    // 4096 floats = 1024 vf4s; 256 threads -> 4 vf4 each (registers).
    vf4 v0 = __builtin_nontemporal_load(xin + tid);
    vf4 v1 = __builtin_nontemporal_load(xin + tid + 256);
    vf4 v2 = __builtin_nontemporal_load(xin + tid + 512);
    vf4 v3 = __builtin_nontemporal_load(xin + tid + 768);

    float s = (v0.x + v0.y + v0.z + v0.w)
            + (v1.x + v1.y + v1.z + v1.w)
            + (v2.x + v2.y + v2.z + v2.w)
            + (v3.x + v3.y + v3.z + v3.w);

    // Wave-level reduction (wave = 64 lanes on gfx950).
    #pragma unroll
    for (int off = 32; off > 0; off >>= 1)
        s += __shfl_down(s, off, 64);

    __shared__ float ws[4];
    __shared__ float gate_s;
    const int wave = tid >> 6;
    if ((tid & 63) == 0) ws[wave] = s;
    __syncthreads();
    if (tid == 0) {
        float tot = ws[0] + ws[1] + ws[2] + ws[3];
        float zc = w1d[c * 5 + 2] * (tot * (1.0f / (float)HW));
        gate_s = 1.0f / (1.0f + __expf(-zc));
    }
    __syncthreads();
    const float g = gate_s;

    v0 *= g;
    v1 *= g;
    v2 *= g;
    v3 *= g;

    __builtin_nontemporal_store(v0, o + tid);
    __builtin_nontemporal_store(v1, o + tid + 256);
    __builtin_nontemporal_store(v2, o + tid + 512);
    __builtin_nontemporal_store(v3, o + tid + 768);
}

extern "C" void kernel_launch(void* const* d_in, const int* in_sizes, int n_in,
                              void* d_out, int out_size, void* d_ws, size_t ws_size,
                              hipStream_t stream) {
    const float* x    = (const float*)d_in[0];  // (16,512,64,64)
    // d_in[1] = w1x1 (unused), d_in[2] = b1x1 (unused)
    const float* w1d  = (const float*)d_in[3];  // (512,5)
    float* out = (float*)d_out;

    const int planes = 16 * NC;  // 8192 blocks
    mcanet_gate_kernel<<<planes, 256, 0, stream>>>(x, w1d, out);
}